// Round 1
// baseline (732.944 us; speedup 1.0000x reference)
//
#include <hip/hip_runtime.h>
#include <cstdint>

#define D_DIM 768
#define BM 256
#define BN 256
#define BK 64
#define NT 12            // D_DIM / BK
#define BUFB (BM*BK + BN*BK)   // 32 KB per ring slot

typedef int   intx8    __attribute__((ext_vector_type(8)));
typedef float floatx16 __attribute__((ext_vector_type(16)));

#define SCALE_ONE 0x7F7F7F7F  // E8M0 127 = 2^0 in every byte

// ---- helpers ----------------------------------------------------------------

__device__ inline void lds_load16(const void* g, void* lds) {
  __builtin_amdgcn_global_load_lds(
      (const __attribute__((address_space(1))) unsigned int*)g,
      (__attribute__((address_space(3))) unsigned int*)lds,
      16, 0, 0);
}

__device__ inline intx8 ldfrag(const unsigned char* p, int o0, int o1) {
  intx8 r;
  *(int4*)&r       = *(const int4*)(p + o0);
  *((int4*)&r + 1) = *(const int4*)(p + o1);
  return r;
}

// ---- kernel 1: row L2 norm + normalize + cast to fp8 e4m3 (both inputs) -----

__global__ __launch_bounds__(256) void norm_cast_kernel(
    const float* __restrict__ EX, const float* __restrict__ EY,
    unsigned int* __restrict__ XO, unsigned int* __restrict__ YO, int Nx) {
  int row = blockIdx.x * 4 + (threadIdx.x >> 6);
  int lane = threadIdx.x & 63;
  const float* X = (row < Nx) ? EX : EY;
  unsigned int* Y = (row < Nx) ? XO : YO;
  int r = (row < Nx) ? row : (row - Nx);
  const float4* xr = (const float4*)(X + (size_t)r * D_DIM);
  float4 a = xr[lane];
  float4 b = xr[lane + 64];
  float4 c = xr[lane + 128];
  float ss = a.x*a.x + a.y*a.y + a.z*a.z + a.w*a.w
           + b.x*b.x + b.y*b.y + b.z*b.z + b.w*b.w
           + c.x*c.x + c.y*c.y + c.z*c.z + c.w*c.w;
  #pragma unroll
  for (int off = 32; off > 0; off >>= 1) ss += __shfl_xor(ss, off, 64);
  float s = 1.0f / fmaxf(sqrtf(ss), 1e-8f);
  unsigned int* yr = Y + (size_t)r * (D_DIM / 4);
  int d;
  d = __builtin_amdgcn_cvt_pk_fp8_f32(a.x * s, a.y * s, 0, false);
  d = __builtin_amdgcn_cvt_pk_fp8_f32(a.z * s, a.w * s, d, true);
  yr[lane] = (unsigned int)d;
  d = __builtin_amdgcn_cvt_pk_fp8_f32(b.x * s, b.y * s, 0, false);
  d = __builtin_amdgcn_cvt_pk_fp8_f32(b.z * s, b.w * s, d, true);
  yr[lane + 64] = (unsigned int)d;
  d = __builtin_amdgcn_cvt_pk_fp8_f32(c.x * s, c.y * s, 0, false);
  d = __builtin_amdgcn_cvt_pk_fp8_f32(c.z * s, c.w * s, d, true);
  yr[lane + 128] = (unsigned int)d;
}

// ---- kernel 2: MX-fp8 MFMA GEMM (S = A . B^T) fused with per-row max --------
//
// 256x256 tile, 8 waves (2x4), wave tile 128x64 = 4x2 of 32x32, BK=64 (one
// K=64 mfma step per tile), 3-deep LDS ring (96 KB), counted vmcnt(4) + ONE
// raw s_barrier per K-tile (T3/T4), setprio around the MFMA cluster (T5).
//
// Ring safety with a single barrier: stage(t+2) targets slot (t+2)%3 ==
// (t-1)%3, i.e. the slot consumed at iteration t-1. Any wave that passed
// barrier(t) has issued mfma(t-1), which (by register dependence) means its
// ds_reads of slot (t-1)%3 are retired -> overwrite is race-free.
//
// LDS rows are 64 B; 16-B chunks stored swizzled: phys = j ^ (row&3), applied
// identically on the global source (staging) and the ds_read offset (both-
// sides involution, rule #21).

#define STAGE(T) do {                                                          \
    unsigned char* dst_ = &lds[(T) % 3][0];                                    \
    const int koff_ = (T) * BK;                                                \
    lds_load16(gA + koff_,       dst_ + wave * 2048);                          \
    lds_load16(gA + koff_ + g16, dst_ + wave * 2048 + 1024);                   \
    lds_load16(gB + koff_,       dst_ + BM * BK + wave * 2048);                \
    lds_load16(gB + koff_ + g16, dst_ + BM * BK + wave * 2048 + 1024);         \
  } while (0)

#define MFMA(d, va, vb)                                                        \
  d = __builtin_amdgcn_mfma_scale_f32_32x32x64_f8f6f4(                         \
      va, vb, d, 0, 0, 0, SCALE_ONE, 0, SCALE_ONE)

#define KITER(T, VMC, DO_STAGE) do {                                           \
    asm volatile("s_waitcnt vmcnt(" #VMC ")" ::: "memory");                    \
    __builtin_amdgcn_s_barrier();                                              \
    __builtin_amdgcn_sched_barrier(0);                                         \
    if (DO_STAGE) STAGE((T) + 2);                                              \
    const unsigned char* buf_ = &lds[(T) % 3][0];                              \
    intx8 a0 = ldfrag(buf_ + arow,        o0, o1);                             \
    intx8 a1 = ldfrag(buf_ + arow + 2048, o0, o1);                             \
    intx8 a2 = ldfrag(buf_ + arow + 4096, o0, o1);                             \
    intx8 a3 = ldfrag(buf_ + arow + 6144, o0, o1);                             \
    intx8 b0 = ldfrag(buf_ + brow,        o0, o1);                             \
    intx8 b1 = ldfrag(buf_ + brow + 2048, o0, o1);                             \
    __builtin_amdgcn_s_setprio(1);                                             \
    MFMA(acc[0][0], a0, b0);                                                   \
    MFMA(acc[1][0], a1, b0);                                                   \
    MFMA(acc[2][0], a2, b0);                                                   \
    MFMA(acc[3][0], a3, b0);                                                   \
    MFMA(acc[0][1], a0, b1);                                                   \
    MFMA(acc[1][1], a1, b1);                                                   \
    MFMA(acc[2][1], a2, b1);                                                   \
    MFMA(acc[3][1], a3, b1);                                                   \
    __builtin_amdgcn_s_setprio(0);                                             \
  } while (0)

__global__ __launch_bounds__(512, 2) void gemm_max_kernel(
    const unsigned char* __restrict__ A,   // exn [Nx x 768] fp8
    const unsigned char* __restrict__ B,   // eyn [Ny x 768] fp8
    float* __restrict__ partial,           // [ncb][Nx]
    int Nx) {
  __shared__ unsigned char lds[3][BUFB];   // 96 KB ring

  const int tid  = threadIdx.x;
  const int wave = tid >> 6;       // 0..7
  const int lane = tid & 63;
  const int wm = wave >> 2;        // 0..1: 128-row half
  const int wn = wave & 3;         // 0..3: 64-col quarter
  const int l31 = lane & 31;
  const int h   = lane >> 5;       // half-wave: k-block selector

  const int bm0 = blockIdx.x * BM;
  const int bn0 = blockIdx.y * BN;

  floatx16 acc[4][2];
  #pragma unroll
  for (int m = 0; m < 4; ++m)
    #pragma unroll
    for (int n = 0; n < 2; ++n)
      acc[m][n] = (floatx16)(0.f);

  // reader-side addresses: row r holds logical chunk c at phys c ^ (r&3);
  // all frag rows are == l31 (mod 4).
  const int akey = l31 & 3;
  const int o0 = ((2 * h + 0) ^ akey) * 16;
  const int o1 = ((2 * h + 1) ^ akey) * 16;
  const int arow = (wm * 128 + l31) * 64;            // + m*2048
  const int brow = BM * BK + (wn * 64 + l31) * 64;   // + n*2048

  // staging: each wave owns 32 A rows and 32 B rows per tile (2 deposits of
  // 16 rows each). Deposit is linear (base + lane*16); the swizzle lives in
  // the per-lane GLOBAL address: row = wave*32 + i*16 + (lane>>2),
  // src chunk j = (lane&3) ^ (row&3).
  const int srow = lane >> 2;
  const int sj = (lane & 3) ^ (srow & 3);
  const unsigned char* gA = A + (size_t)(bm0 + wave * 32 + srow) * D_DIM + sj * 16;
  const unsigned char* gB = B + (size_t)(bn0 + wave * 32 + srow) * D_DIM + sj * 16;
  const size_t g16 = (size_t)16 * D_DIM;

  STAGE(0);
  STAGE(1);

  KITER(0, 4, 1);  KITER(1, 4, 1);  KITER(2, 4, 1);  KITER(3, 4, 1);
  KITER(4, 4, 1);  KITER(5, 4, 1);  KITER(6, 4, 1);  KITER(7, 4, 1);
  KITER(8, 4, 1);  KITER(9, 4, 1);
  KITER(10, 4, 0);                  // tile 12 doesn't exist
  KITER(11, 0, 0);                  // drain: only tile 11's loads remain

  // epilogue: per-row max over this block's 256 columns.
  // C/D (32x32): col = l31 (+n*32+wn*64), row = (reg&3)+8*(reg>>2)+4*h
  // (+m*32+wm*128). red[] aliases ring slot 0: dead since barrier(10).
  float* red = (float*)&lds[0][0];   // [4][256]
  #pragma unroll
  for (int m = 0; m < 4; ++m) {
    #pragma unroll
    for (int reg = 0; reg < 16; ++reg) {
      float v = fmaxf(acc[m][0][reg], acc[m][1][reg]);
      #pragma unroll
      for (int off = 1; off < 32; off <<= 1)
        v = fmaxf(v, __shfl_xor(v, off, 64));   // reduce within each 32-half
      if (l31 == 0) {
        int r = wm * 128 + m * 32 + (reg & 3) + 8 * (reg >> 2) + 4 * h;
        red[wn * 256 + r] = v;
      }
    }
  }
  __syncthreads();
  if (tid < BM) {
    float mv = fmaxf(fmaxf(red[tid], red[256 + tid]),
                     fmaxf(red[512 + tid], red[768 + tid]));
    partial[(size_t)blockIdx.y * Nx + bm0 + tid] = mv;
  }
}

// ---- kernel 3: row max over column blocks + halfnormal transform + block sum

__global__ __launch_bounds__(256) void rowmax_kernel(
    const float* __restrict__ partial, float* __restrict__ bsum, int Nx, int ncb) {
  __shared__ float sdata[4];
  int r = blockIdx.x * blockDim.x + threadIdx.x;
  float m = -1e30f;
  for (int cb = 0; cb < ncb; ++cb)
    m = fmaxf(m, partial[(size_t)cb * Nx + r]);
  float x = 1.0f - m;
  const float logc = -0.22579135264472744f;  // 0.5*log(2/pi), sigma=1
  float l = logc - 0.5f * x * x;
  float t = -__expf(l) * l;
  #pragma unroll
  for (int off = 32; off > 0; off >>= 1) t += __shfl_xor(t, off, 64);
  int wave = threadIdx.x >> 6;
  int lane = threadIdx.x & 63;
  if (lane == 0) sdata[wave] = t;
  __syncthreads();
  if (threadIdx.x == 0)
    bsum[blockIdx.x] = sdata[0] + sdata[1] + sdata[2] + sdata[3];
}

// ---- kernel 4: final sum of block partials -> out[0], out[1] ----------------

__global__ __launch_bounds__(64) void final_kernel(
    const float* __restrict__ bsum, float* __restrict__ out, int nb) {
  int lane = threadIdx.x;
  float s = (lane < nb) ? bsum[lane] : 0.f;
  #pragma unroll
  for (int off = 32; off > 0; off >>= 1) s += __shfl_xor(s, off, 64);
  if (lane == 0) { out[0] = s; out[1] = s; }
}

// ---- launch -----------------------------------------------------------------

extern "C" void kernel_launch(void* const* d_in, const int* in_sizes, int n_in,
                              void* d_out, int out_size, void* d_ws, size_t ws_size,
                              hipStream_t stream) {
  const float* ex = (const float*)d_in[0];
  const float* ey = (const float*)d_in[1];
  const int Nx = in_sizes[0] / D_DIM;   // 8192
  const int Ny = in_sizes[1] / D_DIM;   // 16384
  const int ncb = Ny / BN;              // 64

  char* ws = (char*)d_ws;
  unsigned char* exn = (unsigned char*)ws;                                   // Nx*768 fp8
  unsigned char* eyn = exn + (size_t)Nx * D_DIM;                             // Ny*768 fp8
  float* partial = (float*)(ws + (size_t)(Nx + Ny) * D_DIM);                 // ncb*Nx f32
  float* bsum    = partial + (size_t)ncb * Nx;                               // 32 f32

  norm_cast_kernel<<<(Nx + Ny) / 4, 256, 0, stream>>>(
      ex, ey, (unsigned int*)exn, (unsigned int*)eyn, Nx);
  gemm_max_kernel<<<dim3(Nx / BM, Ny / BN), 512, 0, stream>>>(exn, eyn, partial, Nx);
  rowmax_kernel<<<Nx / 256, 256, 0, stream>>>(partial, bsum, Nx, ncb);
  final_kernel<<<1, 64, 0, stream>>>(bsum, (float*)d_out, Nx / 256);
}

// Round 2
// 280.823 us; speedup vs baseline: 2.6100x; 2.6100x over previous
//
#include <hip/hip_runtime.h>
#include <cstdint>

#define D_DIM 768
#define BM 128
#define BN 256
#define BK 64
#define NT 12                    // D_DIM / BK
#define ABYTES (BM * BK)         // 8 KB
#define SLOT   (BM * BK + BN * BK)  // 24 KB per ring slot

typedef int   intx8    __attribute__((ext_vector_type(8)));
typedef float floatx16 __attribute__((ext_vector_type(16)));

#define SCALE_ONE 0x7F7F7F7F  // E8M0 127 = 2^0 in every byte

// ---- helpers ----------------------------------------------------------------

__device__ inline void lds_load16(const void* g, void* lds) {
  __builtin_amdgcn_global_load_lds(
      (const __attribute__((address_space(1))) unsigned int*)g,
      (__attribute__((address_space(3))) unsigned int*)lds,
      16, 0, 0);
}

__device__ inline intx8 ldfrag(const unsigned char* p, int o0, int o1) {
  intx8 r;
  *(int4*)&r       = *(const int4*)(p + o0);
  *((int4*)&r + 1) = *(const int4*)(p + o1);
  return r;
}

// ---- kernel 1: row L2 norm + normalize + cast to fp8 e4m3 (both inputs) -----

__global__ __launch_bounds__(256) void norm_cast_kernel(
    const float* __restrict__ EX, const float* __restrict__ EY,
    unsigned int* __restrict__ XO, unsigned int* __restrict__ YO, int Nx) {
  int row = blockIdx.x * 4 + (threadIdx.x >> 6);
  int lane = threadIdx.x & 63;
  const float* X = (row < Nx) ? EX : EY;
  unsigned int* Y = (row < Nx) ? XO : YO;
  int r = (row < Nx) ? row : (row - Nx);
  const float4* xr = (const float4*)(X + (size_t)r * D_DIM);
  float4 a = xr[lane];
  float4 b = xr[lane + 64];
  float4 c = xr[lane + 128];
  float ss = a.x*a.x + a.y*a.y + a.z*a.z + a.w*a.w
           + b.x*b.x + b.y*b.y + b.z*b.z + b.w*b.w
           + c.x*c.x + c.y*c.y + c.z*c.z + c.w*c.w;
  #pragma unroll
  for (int off = 32; off > 0; off >>= 1) ss += __shfl_xor(ss, off, 64);
  float s = 1.0f / fmaxf(sqrtf(ss), 1e-8f);
  unsigned int* yr = Y + (size_t)r * (D_DIM / 4);
  int d;
  d = __builtin_amdgcn_cvt_pk_fp8_f32(a.x * s, a.y * s, 0, false);
  d = __builtin_amdgcn_cvt_pk_fp8_f32(a.z * s, a.w * s, d, true);
  yr[lane] = (unsigned int)d;
  d = __builtin_amdgcn_cvt_pk_fp8_f32(b.x * s, b.y * s, 0, false);
  d = __builtin_amdgcn_cvt_pk_fp8_f32(b.z * s, b.w * s, d, true);
  yr[lane + 64] = (unsigned int)d;
  d = __builtin_amdgcn_cvt_pk_fp8_f32(c.x * s, c.y * s, 0, false);
  d = __builtin_amdgcn_cvt_pk_fp8_f32(c.z * s, c.w * s, d, true);
  yr[lane + 128] = (unsigned int)d;
}

// ---- kernel 2: MX-fp8 MFMA GEMM (S = A . B^T) fused with per-row max --------
//
// Round-0's proven register shape (4 waves, 128x256, acc[2][4], VGPR 108) +
// T3/T4 retrofit: BK=64, 3-slot LDS ring (72 KB, still 2 blocks/CU), ONE raw
// s_barrier per K-tile, counted s_waitcnt vmcnt(6) (never 0 mid-loop),
// 2-tile-ahead prefetch. Induction: at iter t's wait, outstanding = tiles
// {t, t+1} (12 loads); vmcnt(6) retires exactly tile t (FIFO, m135).
// Ring safety: STAGE(t+2) writes slot (t+2)%3 == (t-1)%3, whose ds_reads were
// retired before any wave issued iter t-1's MFMAs (lgkmcnt order), hence
// before any wave passed barrier(t).
//
// LDS rows 64 B = 4 x 16B chunks, stored swizzled phys = j ^ (row&3); same
// involution on the per-lane GLOBAL source (staging) and the ds_read offset
// (both-sides rule). This layout's math is correctness-verified (round 1
// passed with absmax 0).
//
// R1 lesson: 8-wave + full 12-iter unroll spilled ~1.2 KB/thread (2.4 GB
// scratch traffic == the whole runtime). Loop stays rolled (unroll 1),
// hand-tripled only to make ring-slot indices compile-time.

#define STAGE(SL, KO) do {                                                     \
    unsigned char* dst_ = lds + (SL) * SLOT;                                   \
    lds_load16(gA + (KO),            dst_ + wave * 2048);                      \
    lds_load16(gA + (KO) + g16,      dst_ + wave * 2048 + 1024);               \
    lds_load16(gB + (KO),            dst_ + ABYTES + wave * 4096);             \
    lds_load16(gB + (KO) + g16,      dst_ + ABYTES + wave * 4096 + 1024);      \
    lds_load16(gB + (KO) + 2 * g16,  dst_ + ABYTES + wave * 4096 + 2048);      \
    lds_load16(gB + (KO) + 3 * g16,  dst_ + ABYTES + wave * 4096 + 3072);      \
  } while (0)

#define MFMA(d, va, vb)                                                        \
  d = __builtin_amdgcn_mfma_scale_f32_32x32x64_f8f6f4(                         \
      va, vb, d, 0, 0, 0, SCALE_ONE, 0, SCALE_ONE)

#define COMPUTE(SL) do {                                                       \
    const unsigned char* buf_ = lds + (SL) * SLOT;                             \
    intx8 a0 = ldfrag(buf_ + arow,        o0, o1);                             \
    intx8 a1 = ldfrag(buf_ + arow + 2048, o0, o1);                             \
    intx8 b;                                                                   \
    __builtin_amdgcn_s_setprio(1);                                             \
    b = ldfrag(buf_ + brow, o0, o1);                                           \
    MFMA(acc[0][0], a0, b);                                                    \
    MFMA(acc[1][0], a1, b);                                                    \
    b = ldfrag(buf_ + brow + 2048, o0, o1);                                    \
    MFMA(acc[0][1], a0, b);                                                    \
    MFMA(acc[1][1], a1, b);                                                    \
    b = ldfrag(buf_ + brow + 4096, o0, o1);                                    \
    MFMA(acc[0][2], a0, b);                                                    \
    MFMA(acc[1][2], a1, b);                                                    \
    b = ldfrag(buf_ + brow + 6144, o0, o1);                                    \
    MFMA(acc[0][3], a0, b);                                                    \
    MFMA(acc[1][3], a1, b);                                                    \
    __builtin_amdgcn_s_setprio(0);                                             \
  } while (0)

#define WAITB(VMC) do {                                                        \
    asm volatile("s_waitcnt vmcnt(" #VMC ")" ::: "memory");                    \
    __builtin_amdgcn_s_barrier();                                              \
  } while (0)

__global__ __launch_bounds__(256, 2) void gemm_max_kernel(
    const unsigned char* __restrict__ A,   // exn [Nx x 768] fp8
    const unsigned char* __restrict__ B,   // eyn [Ny x 768] fp8
    float* __restrict__ partial,           // [ncb][Nx]
    int Nx) {
  __shared__ unsigned char lds[3 * SLOT];  // 72 KB ring
  __shared__ float red[2][BM];             // 1 KB

  const int tid  = threadIdx.x;
  const int wave = tid >> 6;
  const int lane = tid & 63;
  const int wm = wave >> 1;        // 0..1: row half (64 rows)
  const int wn = wave & 1;         // 0..1: col half (128 cols)
  const int l31 = lane & 31;
  const int h   = lane >> 5;       // half-wave: k 32B-half selector

  // T1: supertile XCD swizzle. 64x64 block grid, 8 XCDs; XCD c owns the
  // supertile row gy=c (8 supertiles of 8x8 blocks). Concurrent 64 blocks per
  // XCD form one 8x8 supertile: working set 8 A-panels + 8 B-panels ~2.3 MB
  // < 4 MB XCD L2. Bijective for 64x64 grids.
  const int lid    = blockIdx.y * gridDim.x + blockIdx.x;
  const int xcd    = lid & 7;
  const int idx    = lid >> 3;       // 0..511
  const int sgrp   = idx >> 6;       // 0..7
  const int within = idx & 63;
  const int bx = sgrp * 8 + (within & 7);
  const int by = xcd * 8 + (within >> 3);

  const int bm0 = bx * BM;
  const int bn0 = by * BN;

  floatx16 acc[2][4];
  #pragma unroll
  for (int mt = 0; mt < 2; ++mt)
    #pragma unroll
    for (int nt = 0; nt < 4; ++nt)
      acc[mt][nt] = (floatx16)(0.f);

  // reader-side addresses: row r holds logical chunk c at phys c ^ (r&3).
  const int akey = l31 & 3;
  const int o0 = ((2 * h + 0) ^ akey) * 16;
  const int o1 = ((2 * h + 1) ^ akey) * 16;
  const int arow = (wm * 64 + l31) * 64;             // + mt*2048
  const int brow = ABYTES + (wn * 128 + l31) * 64;   // + nt*2048

  // staging: per tile each wave deposits 32 A rows (2x 1KB) + 64 B rows
  // (4x 1KB); deposit linear, swizzle pre-applied on the global source:
  // lane -> row lane>>2, src chunk (lane&3)^(row&3).
  const int srow = lane >> 2;
  const int sj = (lane & 3) ^ (srow & 3);
  const unsigned char* gA = A + (size_t)(bm0 + wave * 32 + srow) * D_DIM + sj * 16;
  const unsigned char* gB = B + (size_t)(bn0 + wave * 64 + srow) * D_DIM + sj * 16;
  const size_t g16 = (size_t)16 * D_DIM;

  STAGE(0, 0);
  STAGE(1, BK);

  #pragma unroll 1
  for (int t0 = 0; t0 < 9; t0 += 3) {
    const int kb = t0 * BK;
    WAITB(6); STAGE(2, kb + 2 * BK); COMPUTE(0);
    WAITB(6); STAGE(0, kb + 3 * BK); COMPUTE(1);
    WAITB(6); STAGE(1, kb + 4 * BK); COMPUTE(2);
  }
  WAITB(6); STAGE(2, 11 * BK); COMPUTE(0);   // t=9
  WAITB(6);                    COMPUTE(1);   // t=10
  WAITB(0);                    COMPUTE(2);   // t=11 (drain)

  // epilogue: per-row max over this block's 256 columns.
  // C/D (32x32): col = l31 (+nt*32+wn*128), row = (reg&3)+8*(reg>>2)+4*h
  // (+mt*32+wm*64)
  #pragma unroll
  for (int mt = 0; mt < 2; ++mt) {
    #pragma unroll
    for (int reg = 0; reg < 16; ++reg) {
      float v = fmaxf(fmaxf(acc[mt][0][reg], acc[mt][1][reg]),
                      fmaxf(acc[mt][2][reg], acc[mt][3][reg]));
      #pragma unroll
      for (int off = 1; off < 32; off <<= 1)
        v = fmaxf(v, __shfl_xor(v, off, 64));   // reduce within each 32-half
      if (l31 == 0) {
        int r = wm * 64 + mt * 32 + (reg & 3) + 8 * (reg >> 2) + 4 * h;
        red[wn][r] = v;
      }
    }
  }
  __syncthreads();
  if (tid < BM) {
    float m = fmaxf(red[0][tid], red[1][tid]);
    partial[(size_t)by * Nx + bm0 + tid] = m;
  }
}

// ---- kernel 3: row max over column blocks + halfnormal transform + block sum

__global__ __launch_bounds__(256) void rowmax_kernel(
    const float* __restrict__ partial, float* __restrict__ bsum, int Nx, int ncb) {
  __shared__ float sdata[4];
  int r = blockIdx.x * blockDim.x + threadIdx.x;
  float m = -1e30f;
  for (int cb = 0; cb < ncb; ++cb)
    m = fmaxf(m, partial[(size_t)cb * Nx + r]);
  float x = 1.0f - m;
  const float logc = -0.22579135264472744f;  // 0.5*log(2/pi), sigma=1
  float l = logc - 0.5f * x * x;
  float t = -__expf(l) * l;
  #pragma unroll
  for (int off = 32; off > 0; off >>= 1) t += __shfl_xor(t, off, 64);
  int wave = threadIdx.x >> 6;
  int lane = threadIdx.x & 63;
  if (lane == 0) sdata[wave] = t;
  __syncthreads();
  if (threadIdx.x == 0)
    bsum[blockIdx.x] = sdata[0] + sdata[1] + sdata[2] + sdata[3];
}

// ---- kernel 4: final sum of block partials -> out[0], out[1] ----------------

__global__ __launch_bounds__(64) void final_kernel(
    const float* __restrict__ bsum, float* __restrict__ out, int nb) {
  int lane = threadIdx.x;
  float s = (lane < nb) ? bsum[lane] : 0.f;
  #pragma unroll
  for (int off = 32; off > 0; off >>= 1) s += __shfl_xor(s, off, 64);
  if (lane == 0) { out[0] = s; out[1] = s; }
}

// ---- launch -----------------------------------------------------------------

extern "C" void kernel_launch(void* const* d_in, const int* in_sizes, int n_in,
                              void* d_out, int out_size, void* d_ws, size_t ws_size,
                              hipStream_t stream) {
  const float* ex = (const float*)d_in[0];
  const float* ey = (const float*)d_in[1];
  const int Nx = in_sizes[0] / D_DIM;   // 8192
  const int Ny = in_sizes[1] / D_DIM;   // 16384
  const int ncb = Ny / BN;              // 64

  char* ws = (char*)d_ws;
  unsigned char* exn = (unsigned char*)ws;                                   // Nx*768 fp8
  unsigned char* eyn = exn + (size_t)Nx * D_DIM;                             // Ny*768 fp8
  float* partial = (float*)(ws + (size_t)(Nx + Ny) * D_DIM);                 // ncb*Nx f32
  float* bsum    = partial + (size_t)ncb * Nx;                               // 32 f32

  norm_cast_kernel<<<(Nx + Ny) / 4, 256, 0, stream>>>(
      ex, ey, (unsigned int*)exn, (unsigned int*)eyn, Nx);
  gemm_max_kernel<<<dim3(Nx / BM, Ny / BN), 256, 0, stream>>>(exn, eyn, partial, Nx);
  rowmax_kernel<<<Nx / 256, 256, 0, stream>>>(partial, bsum, Nx, ncb);
  final_kernel<<<1, 64, 0, stream>>>(bsum, (float*)d_out, Nx / 256);
}